// Round 12
// baseline (235.488 us; speedup 1.0000x reference)
//
#include <hip/hip_runtime.h>
#include <math.h>

#define V_ 32000
#define E_ 512
#define H_ 1024
#define N_ 64
#define S_ 2048

typedef short bf16x8 __attribute__((ext_vector_type(8)));
typedef float f32x4 __attribute__((ext_vector_type(4)));

__device__ __forceinline__ float sigmoidf_(float x) { return 1.0f / (1.0f + expf(-x)); }

__device__ __forceinline__ unsigned f2bf_u(float f) {  // RNE f32->bf16 bits
  unsigned a = __float_as_uint(f);
  return (a + 0x7fffu + ((a >> 16) & 1u)) >> 16;
}
__device__ __forceinline__ unsigned pk2(float lo, float hi) {
  return f2bf_u(lo) | (f2bf_u(hi) << 16);
}
__device__ __forceinline__ unsigned short f2bf(float f) { return (unsigned short)f2bf_u(f); }

// ---------------------------------------------------------------------------
// f32 gates GEMM, K-split x8 (512 blocks = 2/CU; was 1/CU grid-starved).
// Transposed store Cpart[part][n][j]. Z built in-kernel (round-7 proven).
// ---------------------------------------------------------------------------
__global__ __launch_bounds__(256) void k_gemm64t(
    const float* __restrict__ W1, const float* __restrict__ W2,
    const int* __restrict__ prev_out, const float* __restrict__ embW,
    const float* __restrict__ h0, float* __restrict__ Cpart, int klen) {
  const int t = threadIdx.x;
  const int j0 = blockIdx.x * 64;
  const int part = blockIdx.y;
  const int kbeg = part * klen;
  const int kend = kbeg + klen;

  __shared__ float zt[32][68];
  __shared__ float wt[32][68];

  const int tc = t & 15;
  const int tr = t >> 4;
  const int jw = t >> 2;
  const int kq = (t & 3) * 8;

  const int zrow = prev_out[jw];

  float acc[4][4];
#pragma unroll
  for (int i = 0; i < 4; i++)
#pragma unroll
    for (int j = 0; j < 4; j++) acc[i][j] = 0.f;

  for (int k0 = kbeg; k0 < kend; k0 += 32) {
    const float* zsrc;
    const float* wrow;
    if (k0 < E_) {
      zsrc = embW + (size_t)zrow * E_ + k0 + kq;
      wrow = W1 + (size_t)(j0 + jw) * E_ + k0 + kq;
    } else {
      zsrc = h0 + (size_t)jw * H_ + (k0 - E_) + kq;
      wrow = W2 + (size_t)(j0 + jw) * H_ + (k0 - E_) + kq;
    }
    float4 za = *(const float4*)(zsrc);
    float4 zb = *(const float4*)(zsrc + 4);
    float4 wa = *(const float4*)(wrow);
    float4 wb = *(const float4*)(wrow + 4);

    __syncthreads();
    zt[kq + 0][jw] = za.x; zt[kq + 1][jw] = za.y;
    zt[kq + 2][jw] = za.z; zt[kq + 3][jw] = za.w;
    zt[kq + 4][jw] = zb.x; zt[kq + 5][jw] = zb.y;
    zt[kq + 6][jw] = zb.z; zt[kq + 7][jw] = zb.w;
    wt[kq + 0][jw] = wa.x; wt[kq + 1][jw] = wa.y;
    wt[kq + 2][jw] = wa.z; wt[kq + 3][jw] = wa.w;
    wt[kq + 4][jw] = wb.x; wt[kq + 5][jw] = wb.y;
    wt[kq + 6][jw] = wb.z; wt[kq + 7][jw] = wb.w;
    __syncthreads();

#pragma unroll 8
    for (int k = 0; k < 32; k++) {
      float4 z = *(const float4*)(&zt[k][tc * 4]);
      float4 w = *(const float4*)(&wt[k][tr * 4]);
      acc[0][0] += w.x * z.x; acc[0][1] += w.x * z.y; acc[0][2] += w.x * z.z; acc[0][3] += w.x * z.w;
      acc[1][0] += w.y * z.x; acc[1][1] += w.y * z.y; acc[1][2] += w.y * z.z; acc[1][3] += w.y * z.w;
      acc[2][0] += w.z * z.x; acc[2][1] += w.z * z.y; acc[2][2] += w.z * z.z; acc[2][3] += w.z * z.w;
      acc[3][0] += w.w * z.x; acc[3][1] += w.w * z.y; acc[3][2] += w.w * z.z; acc[3][3] += w.w * z.w;
    }
  }

  float* cp = Cpart + (size_t)part * 4096 * 64;  // [n][j]
#pragma unroll
  for (int nn = 0; nn < 4; nn++) {
    int n = tc * 4 + nn;
    float4 o = make_float4(acc[0][nn], acc[1][nn], acc[2][nn], acc[3][nn]);
    *(float4*)(cp + (size_t)n * 4096 + j0 + tr * 4) = o;
  }
}

// ---------------------------------------------------------------------------
// LSTM cell + K-split reduce (8 partials, coalesced via transposed gpart)
// ---------------------------------------------------------------------------
__global__ __launch_bounds__(256) void k_lstm_fused(
    const float* __restrict__ gpart, const float* __restrict__ b_ih,
    const float* __restrict__ b_hh, const float* __restrict__ c0,
    float* __restrict__ out_h, float* __restrict__ out_c,
    unsigned short* __restrict__ concat_bf) {
  int idx = blockIdx.x * 256 + threadIdx.x;  // 64*1024
  int n = idx >> 10, hh = idx & 1023;
  float g[4];
#pragma unroll
  for (int ga = 0; ga < 4; ga++) {
    float s = b_ih[ga * H_ + hh] + b_hh[ga * H_ + hh];
#pragma unroll
    for (int p = 0; p < 8; p++)
      s += gpart[((size_t)p * 64 + n) * 4096 + ga * H_ + hh];
    g[ga] = s;
  }
  float cv = sigmoidf_(g[1]) * c0[idx] + sigmoidf_(g[0]) * tanhf(g[2]);
  float hv = sigmoidf_(g[3]) * tanhf(cv);
  out_h[idx] = hv;
  out_c[idx] = cv;
  concat_bf[(size_t)n * 2048 + hh] = f2bf(hv);
}

// ---------------------------------------------------------------------------
// Fused attention (round-7 proven 1-row body): one enc pass, s-chunk 128.
// ---------------------------------------------------------------------------
__global__ __launch_bounds__(256) void k_attn(
    const float* __restrict__ enc, const float* __restrict__ h,
    float* __restrict__ ctxPart) {
  const int c = blockIdx.x;   // 0..15
  const int n = blockIdx.y;   // 0..63
  const int t = threadIdx.x, w = t >> 6, lane = t & 63;

  __shared__ float hs[H_];
  __shared__ float cbuf[4][H_];
  ((float4*)hs)[t] = ((const float4*)(h + (size_t)n * H_))[t];
  __syncthreads();

  const float4* hp = (const float4*)hs;
  float4 hv0 = hp[lane], hv1 = hp[64 + lane], hv2 = hp[128 + lane], hv3 = hp[192 + lane];

  float ca[16];
#pragma unroll
  for (int i = 0; i < 16; i++) ca[i] = 0.f;

  for (int si = w; si < 128; si += 4) {
    const int s = c * 128 + si;
    const float4* row = (const float4*)(enc + ((size_t)n * S_ + s) * H_);
    float4 e0 = row[lane], e1 = row[64 + lane], e2 = row[128 + lane], e3 = row[192 + lane];
    float d = e0.x * hv0.x + e0.y * hv0.y + e0.z * hv0.z + e0.w * hv0.w
            + e1.x * hv1.x + e1.y * hv1.y + e1.z * hv1.z + e1.w * hv1.w
            + e2.x * hv2.x + e2.y * hv2.y + e2.z * hv2.z + e2.w * hv2.w
            + e3.x * hv3.x + e3.y * hv3.y + e3.z * hv3.z + e3.w * hv3.w;
#pragma unroll
    for (int m = 32; m; m >>= 1) d += __shfl_xor(d, m, 64);
    ca[0]  += d * e0.x; ca[1]  += d * e0.y; ca[2]  += d * e0.z; ca[3]  += d * e0.w;
    ca[4]  += d * e1.x; ca[5]  += d * e1.y; ca[6]  += d * e1.z; ca[7]  += d * e1.w;
    ca[8]  += d * e2.x; ca[9]  += d * e2.y; ca[10] += d * e2.z; ca[11] += d * e2.w;
    ca[12] += d * e3.x; ca[13] += d * e3.y; ca[14] += d * e3.z; ca[15] += d * e3.w;
  }

  float4* cb = (float4*)&cbuf[w][0];
  cb[0 * 64 + lane] = make_float4(ca[0], ca[1], ca[2], ca[3]);
  cb[1 * 64 + lane] = make_float4(ca[4], ca[5], ca[6], ca[7]);
  cb[2 * 64 + lane] = make_float4(ca[8], ca[9], ca[10], ca[11]);
  cb[3 * 64 + lane] = make_float4(ca[12], ca[13], ca[14], ca[15]);
  __syncthreads();

  float4 a0 = ((const float4*)&cbuf[0][0])[t];
  float4 a1 = ((const float4*)&cbuf[1][0])[t];
  float4 a2 = ((const float4*)&cbuf[2][0])[t];
  float4 a3 = ((const float4*)&cbuf[3][0])[t];
  float4 r = make_float4(a0.x + a1.x + a2.x + a3.x, a0.y + a1.y + a2.y + a3.y,
                         a0.z + a1.z + a2.z + a3.z, a0.w + a1.w + a2.w + a3.w);
  ((float4*)ctxPart)[((size_t)(n * 16 + c)) * 256 + t] = r;
}

// ---------------------------------------------------------------------------
// Reduce 16 context partials -> concat ctx half (bf16)
// ---------------------------------------------------------------------------
__global__ __launch_bounds__(256) void k_ctxreduce_bf(
    const float* __restrict__ ctxPart, unsigned short* __restrict__ concat_bf) {
  int idx = blockIdx.x * 256 + threadIdx.x;  // 64*1024
  int n = idx >> 10, hh = idx & 1023;
  float s = 0.f;
  for (int c = 0; c < 16; c++) s += ctxPart[((size_t)(n * 16 + c)) * H_ + hh];
  concat_bf[(size_t)n * 2048 + H_ + hh] = f2bf(s);
}

// ---------------------------------------------------------------------------
// fc GEMM via MFMA bf16 — chunk-128 (BK=128): 32 barrier pairs instead of 64,
// each vmcnt(0)-at-barrier drain amortized over 2x MFMA+LDS work; prefetch
// issued a full 128-k chunk early. LDS 32KB (free: grid-limited 2 blocks/CU).
// Same verified fragment mapping + XOR swizzle (16 slots/row).
// Fused softmax-stats epilogue, transposed statsPart.
// ---------------------------------------------------------------------------
__global__ __launch_bounds__(256) void k_fc_mfma(
    const float* __restrict__ W, const unsigned short* __restrict__ Zbf,
    const float* __restrict__ bias, float* __restrict__ outNV,
    float* __restrict__ statsPart) {
  const int t = threadIdx.x;
  const int v0 = blockIdx.x * 64;
  const int w = t >> 6, lane = t & 63;
  __shared__ __align__(16) unsigned char smem[32768];

  f32x4 acc[4] = {{0.f,0.f,0.f,0.f},{0.f,0.f,0.f,0.f},{0.f,0.f,0.f,0.f},{0.f,0.f,0.f,0.f}};

  // A staging: thread -> row ar (t>>2), k-base (t&3)*32 (32 floats = 8 float4)
  const int ar = t >> 2;
  const int aq = t & 3;
  const float* aptr = W + (size_t)(v0 + ar) * 2048 + aq * 32;
  unsigned awo[4];
#pragma unroll
  for (int j = 0; j < 4; j++)
    awo[j] = ar * 256 + (((aq * 4 + j) * 16) ^ ((ar & 7) << 4));
  // B staging: same shape (row bn=t>>2, 32 k = 4 slots)
  const int bn = t >> 2;
  const unsigned short* bptr = Zbf + (size_t)bn * 2048 + aq * 32;
  unsigned bwo[4];
#pragma unroll
  for (int j = 0; j < 4; j++)
    bwo[j] = 16384 + bn * 256 + (((aq * 4 + j) * 16) ^ ((bn & 7) << 4));

  // fragment read offsets: k-slot = kh*4+ksub (kh 0..3 within 128-k chunk)
  const int arow = (w << 4) + (lane & 15);
  const int ksub = lane >> 4;  // 0..3
  unsigned aro[4];
#pragma unroll
  for (int kh = 0; kh < 4; kh++)
    aro[kh] = arow * 256 + (((kh * 4 + ksub) * 16) ^ ((arow & 7) << 4));
  unsigned bro[4][4];
#pragma unroll
  for (int kh = 0; kh < 4; kh++)
#pragma unroll
    for (int nf = 0; nf < 4; nf++) {
      int brow = nf * 16 + (lane & 15);
      bro[kh][nf] = 16384 + brow * 256 + (((kh * 4 + ksub) * 16) ^ ((brow & 7) << 4));
    }

  // prefetch chunk 0
  float4 pa[8];
  uint4 pb[4];
#pragma unroll
  for (int s = 0; s < 8; s++) pa[s] = ((const float4*)aptr)[s];
#pragma unroll
  for (int j = 0; j < 4; j++) pb[j] = *(const uint4*)(bptr + j * 8);

  for (int c = 0; c < 16; c++) {
    __syncthreads();  // prev chunk's frag reads done
    // pack + store A (4 slots), store B (4 slots)
#pragma unroll
    for (int j = 0; j < 4; j++) {
      uint4 p;
      p.x = pk2(pa[2*j].x,   pa[2*j].y);   p.y = pk2(pa[2*j].z,   pa[2*j].w);
      p.z = pk2(pa[2*j+1].x, pa[2*j+1].y); p.w = pk2(pa[2*j+1].z, pa[2*j+1].w);
      *(uint4*)(smem + awo[j]) = p;
      *(uint4*)(smem + bwo[j]) = pb[j];
    }
    // prefetch next chunk (stays in flight across the MFMA phase)
    if (c < 15) {
      const float* ap = aptr + (c + 1) * 128;
#pragma unroll
      for (int s = 0; s < 8; s++) pa[s] = ((const float4*)ap)[s];
      const unsigned short* bp = bptr + (c + 1) * 128;
#pragma unroll
      for (int j = 0; j < 4; j++) pb[j] = *(const uint4*)(bp + j * 8);
    }
    __syncthreads();  // chunk visible
#pragma unroll
    for (int kh = 0; kh < 4; kh++) {
      bf16x8 af = *(const bf16x8*)(smem + aro[kh]);
#pragma unroll
      for (int nf = 0; nf < 4; nf++) {
        bf16x8 bfr = *(const bf16x8*)(smem + bro[kh][nf]);
        acc[nf] = __builtin_amdgcn_mfma_f32_16x16x32_bf16(af, bfr, acc[nf], 0, 0, 0);
      }
    }
  }

  // epilogue: D col = lane&15 (n within frag), row = (lane>>4)*4 + reg (v)
  const int vrow = v0 + (w << 4) + (ksub << 2);
  float4 b4 = *(const float4*)(bias + vrow);
  float vals[4][4];
#pragma unroll
  for (int nf = 0; nf < 4; nf++) {
    int n = nf * 16 + (lane & 15);
    vals[nf][0] = acc[nf][0] + b4.x; vals[nf][1] = acc[nf][1] + b4.y;
    vals[nf][2] = acc[nf][2] + b4.z; vals[nf][3] = acc[nf][3] + b4.w;
    *(float4*)(outNV + (size_t)n * V_ + vrow) =
        make_float4(vals[nf][0], vals[nf][1], vals[nf][2], vals[nf][3]);
  }

  // fused per-block softmax stats over this 64n x 64v tile
  __syncthreads();  // all frag reads done; reuse smem
  float* mx   = (float*)smem;            // [64][16]
  float* sm   = (float*)(smem + 4096);   // [64][16]
  float* bmax = (float*)(smem + 8192);   // [64]
  const int cidx = w * 4 + ksub;         // 16 contributors per n
#pragma unroll
  for (int nf = 0; nf < 4; nf++) {
    int n = nf * 16 + (lane & 15);
    float m = fmaxf(fmaxf(vals[nf][0], vals[nf][1]), fmaxf(vals[nf][2], vals[nf][3]));
    mx[n * 16 + cidx] = m;
  }
  __syncthreads();
  if (t < 64) {
    float m = mx[t * 16];
#pragma unroll
    for (int i = 1; i < 16; i++) m = fmaxf(m, mx[t * 16 + i]);
    bmax[t] = m;
  }
  __syncthreads();
#pragma unroll
  for (int nf = 0; nf < 4; nf++) {
    int n = nf * 16 + (lane & 15);
    float M = bmax[n];
    float s = expf(vals[nf][0] - M) + expf(vals[nf][1] - M) +
              expf(vals[nf][2] - M) + expf(vals[nf][3] - M);
    sm[n * 16 + cidx] = s;
  }
  __syncthreads();
  if (t < 64) {
    float s = 0.f;
#pragma unroll
    for (int i = 0; i < 16; i++) s += sm[t * 16 + i];
    statsPart[(size_t)t * 1024 + blockIdx.x * 2]     = bmax[t];
    statsPart[(size_t)t * 1024 + blockIdx.x * 2 + 1] = s;
  }
}

// ---------------------------------------------------------------------------
// Merged stats-combine + logp
// ---------------------------------------------------------------------------
__global__ __launch_bounds__(256) void k_logp_merged(
    float* __restrict__ logits, const float* __restrict__ statsPart) {
  const int n = blockIdx.y, t = threadIdx.x;
  const float2* sp = (const float2*)(statsPart + (size_t)n * 1024);

  float m = -INFINITY, s = 0.f;
#pragma unroll
  for (int rep = 0; rep < 2; rep++) {
    int p = rep * 256 + t;
    if (p < 500) {
      float2 e = sp[p];
      if (e.x > m) { s = s * expf(m - e.x) + e.y; m = e.x; }
      else         { s += e.y * expf(e.x - m); }
    }
  }
  __shared__ float ms[256], ss[256];
  ms[t] = m; ss[t] = s;
  __syncthreads();
  for (int off = 128; off; off >>= 1) {
    if (t < off) {
      float m2 = ms[t + off], s2 = ss[t + off];
      float M = fmaxf(ms[t], m2);
      ss[t] = ss[t] * expf(ms[t] - M) + s2 * expf(m2 - M);
      ms[t] = M;
    }
    __syncthreads();
  }
  const float sub = ms[0] + logf(ss[0]);

  const int v4 = blockIdx.x * 256 + t;  // float4 index, 8000 per row
  if (v4 < V_ / 4) {
    float4* p = (float4*)(logits + (size_t)n * V_) + v4;
    float4 x = *p;
    *p = make_float4(x.x - sub, x.y - sub, x.z - sub, x.w - sub);
  }
}

// ---------------------------------------------------------------------------
extern "C" void kernel_launch(void* const* d_in, const int* in_sizes, int n_in,
                              void* d_out, int out_size, void* d_ws, size_t ws_size,
                              hipStream_t stream) {
  const int*   prev_out = (const int*)d_in[0];
  const float* h0   = (const float*)d_in[1];
  const float* c0   = (const float*)d_in[2];
  const float* enc  = (const float*)d_in[3];
  const float* embW = (const float*)d_in[4];
  const float* w_ih = (const float*)d_in[5];
  const float* w_hh = (const float*)d_in[6];
  const float* b_ih = (const float*)d_in[7];
  const float* b_hh = (const float*)d_in[8];
  const float* fc_W = (const float*)d_in[9];
  const float* fc_b = (const float*)d_in[10];

  float* out = (float*)d_out;
  float* logp  = out;                       // N*V (logits -> logp in place)
  float* out_h = out + (size_t)N_ * V_;     // N*H
  float* out_c = out_h + (size_t)N_ * H_;   // N*H

  char* wsb = (char*)d_ws;
  float* gpart   = (float*)wsb; wsb += (size_t)8 * 4096 * 64 * 4;      // 8 MB
  float* ctxPart = (float*)wsb; wsb += (size_t)16 * 64 * H_ * 4;       // 4 MB
  unsigned short* concat_bf = (unsigned short*)wsb; wsb += (size_t)64 * 2048 * 2;
  float* statsPart = (float*)wsb; wsb += (size_t)64 * 1024 * 4;        // 256 KB

  // 1. gates (K-split x8 -> 512 blocks, in-kernel Z gather, transposed store)
  k_gemm64t<<<dim3(4096 / 64, 8), 256, 0, stream>>>(
      w_ih, w_hh, prev_out, embW, h0, gpart, 192);
  // 2. LSTM -> h,c (d_out), h -> concat_bf[.., 0:1024)
  k_lstm_fused<<<64 * H_ / 256, 256, 0, stream>>>(gpart, b_ih, b_hh, c0,
                                                  out_h, out_c, concat_bf);
  // 3. attention (single enc pass, r7 proven body)
  k_attn<<<dim3(16, 64), 256, 0, stream>>>(enc, out_h, ctxPart);
  // 4. ctx reduce -> concat_bf[.., 1024:2048)
  k_ctxreduce_bf<<<64 * H_ / 256, 256, 0, stream>>>(ctxPart, concat_bf);
  // 5. fc (chunk-128, plain barriers, fused softmax stats)
  k_fc_mfma<<<V_ / 64, 256, 0, stream>>>(fc_W, concat_bf, fc_b, logp, statsPart);
  // 6. merged stats-combine + in-place logp
  k_logp_merged<<<dim3((V_ / 4 + 255) / 256, N_), 256, 0, stream>>>(logp, statsPart);
}

// Round 13
// 181.115 us; speedup vs baseline: 1.3002x; 1.3002x over previous
//
#include <hip/hip_runtime.h>
#include <math.h>

#define V_ 32000
#define E_ 512
#define H_ 1024
#define N_ 64
#define S_ 2048

typedef short bf16x8 __attribute__((ext_vector_type(8)));
typedef float f32x4 __attribute__((ext_vector_type(4)));

__device__ __forceinline__ float sigmoidf_(float x) { return 1.0f / (1.0f + expf(-x)); }

__device__ __forceinline__ unsigned f2bf_u(float f) {  // RNE f32->bf16 bits
  unsigned a = __float_as_uint(f);
  return (a + 0x7fffu + ((a >> 16) & 1u)) >> 16;
}
__device__ __forceinline__ unsigned pk2(float lo, float hi) {
  return f2bf_u(lo) | (f2bf_u(hi) << 16);
}
__device__ __forceinline__ unsigned short f2bf(float f) { return (unsigned short)f2bf_u(f); }

// ---------------------------------------------------------------------------
// f32 gates GEMM, K-split x8 (512 blocks = 2/CU), transposed store
// Cpart[part][n][j]. Z built in-kernel (round-7 proven body).
// ---------------------------------------------------------------------------
__global__ __launch_bounds__(256) void k_gemm64t(
    const float* __restrict__ W1, const float* __restrict__ W2,
    const int* __restrict__ prev_out, const float* __restrict__ embW,
    const float* __restrict__ h0, float* __restrict__ Cpart, int klen) {
  const int t = threadIdx.x;
  const int j0 = blockIdx.x * 64;
  const int part = blockIdx.y;
  const int kbeg = part * klen;
  const int kend = kbeg + klen;

  __shared__ float zt[32][68];
  __shared__ float wt[32][68];

  const int tc = t & 15;
  const int tr = t >> 4;
  const int jw = t >> 2;
  const int kq = (t & 3) * 8;

  const int zrow = prev_out[jw];

  float acc[4][4];
#pragma unroll
  for (int i = 0; i < 4; i++)
#pragma unroll
    for (int j = 0; j < 4; j++) acc[i][j] = 0.f;

  for (int k0 = kbeg; k0 < kend; k0 += 32) {
    const float* zsrc;
    const float* wrow;
    if (k0 < E_) {
      zsrc = embW + (size_t)zrow * E_ + k0 + kq;
      wrow = W1 + (size_t)(j0 + jw) * E_ + k0 + kq;
    } else {
      zsrc = h0 + (size_t)jw * H_ + (k0 - E_) + kq;
      wrow = W2 + (size_t)(j0 + jw) * H_ + (k0 - E_) + kq;
    }
    float4 za = *(const float4*)(zsrc);
    float4 zb = *(const float4*)(zsrc + 4);
    float4 wa = *(const float4*)(wrow);
    float4 wb = *(const float4*)(wrow + 4);

    __syncthreads();
    zt[kq + 0][jw] = za.x; zt[kq + 1][jw] = za.y;
    zt[kq + 2][jw] = za.z; zt[kq + 3][jw] = za.w;
    zt[kq + 4][jw] = zb.x; zt[kq + 5][jw] = zb.y;
    zt[kq + 6][jw] = zb.z; zt[kq + 7][jw] = zb.w;
    wt[kq + 0][jw] = wa.x; wt[kq + 1][jw] = wa.y;
    wt[kq + 2][jw] = wa.z; wt[kq + 3][jw] = wa.w;
    wt[kq + 4][jw] = wb.x; wt[kq + 5][jw] = wb.y;
    wt[kq + 6][jw] = wb.z; wt[kq + 7][jw] = wb.w;
    __syncthreads();

#pragma unroll 8
    for (int k = 0; k < 32; k++) {
      float4 z = *(const float4*)(&zt[k][tc * 4]);
      float4 w = *(const float4*)(&wt[k][tr * 4]);
      acc[0][0] += w.x * z.x; acc[0][1] += w.x * z.y; acc[0][2] += w.x * z.z; acc[0][3] += w.x * z.w;
      acc[1][0] += w.y * z.x; acc[1][1] += w.y * z.y; acc[1][2] += w.y * z.z; acc[1][3] += w.y * z.w;
      acc[2][0] += w.z * z.x; acc[2][1] += w.z * z.y; acc[2][2] += w.z * z.z; acc[2][3] += w.z * z.w;
      acc[3][0] += w.w * z.x; acc[3][1] += w.w * z.y; acc[3][2] += w.w * z.z; acc[3][3] += w.w * z.w;
    }
  }

  float* cp = Cpart + (size_t)part * 4096 * 64;  // [n][j]
#pragma unroll
  for (int nn = 0; nn < 4; nn++) {
    int n = tc * 4 + nn;
    float4 o = make_float4(acc[0][nn], acc[1][nn], acc[2][nn], acc[3][nn]);
    *(float4*)(cp + (size_t)n * 4096 + j0 + tr * 4) = o;
  }
}

// ---------------------------------------------------------------------------
// LSTM cell + K-split reduce (8 partials, coalesced via transposed gpart)
// ---------------------------------------------------------------------------
__global__ __launch_bounds__(256) void k_lstm_fused(
    const float* __restrict__ gpart, const float* __restrict__ b_ih,
    const float* __restrict__ b_hh, const float* __restrict__ c0,
    float* __restrict__ out_h, float* __restrict__ out_c,
    unsigned short* __restrict__ concat_bf) {
  int idx = blockIdx.x * 256 + threadIdx.x;  // 64*1024
  int n = idx >> 10, hh = idx & 1023;
  float g[4];
#pragma unroll
  for (int ga = 0; ga < 4; ga++) {
    float s = b_ih[ga * H_ + hh] + b_hh[ga * H_ + hh];
#pragma unroll
    for (int p = 0; p < 8; p++)
      s += gpart[((size_t)p * 64 + n) * 4096 + ga * H_ + hh];
    g[ga] = s;
  }
  float cv = sigmoidf_(g[1]) * c0[idx] + sigmoidf_(g[0]) * tanhf(g[2]);
  float hv = sigmoidf_(g[3]) * tanhf(cv);
  out_h[idx] = hv;
  out_c[idx] = cv;
  concat_bf[(size_t)n * 2048 + hh] = f2bf(hv);
}

// ---------------------------------------------------------------------------
// Fused attention (round-7 proven 1-row body): one enc pass, s-chunk 128.
// ---------------------------------------------------------------------------
__global__ __launch_bounds__(256) void k_attn(
    const float* __restrict__ enc, const float* __restrict__ h,
    float* __restrict__ ctxPart) {
  const int c = blockIdx.x;   // 0..15
  const int n = blockIdx.y;   // 0..63
  const int t = threadIdx.x, w = t >> 6, lane = t & 63;

  __shared__ float hs[H_];
  __shared__ float cbuf[4][H_];
  ((float4*)hs)[t] = ((const float4*)(h + (size_t)n * H_))[t];
  __syncthreads();

  const float4* hp = (const float4*)hs;
  float4 hv0 = hp[lane], hv1 = hp[64 + lane], hv2 = hp[128 + lane], hv3 = hp[192 + lane];

  float ca[16];
#pragma unroll
  for (int i = 0; i < 16; i++) ca[i] = 0.f;

  for (int si = w; si < 128; si += 4) {
    const int s = c * 128 + si;
    const float4* row = (const float4*)(enc + ((size_t)n * S_ + s) * H_);
    float4 e0 = row[lane], e1 = row[64 + lane], e2 = row[128 + lane], e3 = row[192 + lane];
    float d = e0.x * hv0.x + e0.y * hv0.y + e0.z * hv0.z + e0.w * hv0.w
            + e1.x * hv1.x + e1.y * hv1.y + e1.z * hv1.z + e1.w * hv1.w
            + e2.x * hv2.x + e2.y * hv2.y + e2.z * hv2.z + e2.w * hv2.w
            + e3.x * hv3.x + e3.y * hv3.y + e3.z * hv3.z + e3.w * hv3.w;
#pragma unroll
    for (int m = 32; m; m >>= 1) d += __shfl_xor(d, m, 64);
    ca[0]  += d * e0.x; ca[1]  += d * e0.y; ca[2]  += d * e0.z; ca[3]  += d * e0.w;
    ca[4]  += d * e1.x; ca[5]  += d * e1.y; ca[6]  += d * e1.z; ca[7]  += d * e1.w;
    ca[8]  += d * e2.x; ca[9]  += d * e2.y; ca[10] += d * e2.z; ca[11] += d * e2.w;
    ca[12] += d * e3.x; ca[13] += d * e3.y; ca[14] += d * e3.z; ca[15] += d * e3.w;
  }

  float4* cb = (float4*)&cbuf[w][0];
  cb[0 * 64 + lane] = make_float4(ca[0], ca[1], ca[2], ca[3]);
  cb[1 * 64 + lane] = make_float4(ca[4], ca[5], ca[6], ca[7]);
  cb[2 * 64 + lane] = make_float4(ca[8], ca[9], ca[10], ca[11]);
  cb[3 * 64 + lane] = make_float4(ca[12], ca[13], ca[14], ca[15]);
  __syncthreads();

  float4 a0 = ((const float4*)&cbuf[0][0])[t];
  float4 a1 = ((const float4*)&cbuf[1][0])[t];
  float4 a2 = ((const float4*)&cbuf[2][0])[t];
  float4 a3 = ((const float4*)&cbuf[3][0])[t];
  float4 r = make_float4(a0.x + a1.x + a2.x + a3.x, a0.y + a1.y + a2.y + a3.y,
                         a0.z + a1.z + a2.z + a3.z, a0.w + a1.w + a2.w + a3.w);
  ((float4*)ctxPart)[((size_t)(n * 16 + c)) * 256 + t] = r;
}

// ---------------------------------------------------------------------------
// Reduce 16 context partials -> concat ctx half (bf16)
// ---------------------------------------------------------------------------
__global__ __launch_bounds__(256) void k_ctxreduce_bf(
    const float* __restrict__ ctxPart, unsigned short* __restrict__ concat_bf) {
  int idx = blockIdx.x * 256 + threadIdx.x;  // 64*1024
  int n = idx >> 10, hh = idx & 1023;
  float s = 0.f;
  for (int c = 0; c < 16; c++) s += ctxPart[((size_t)(n * 16 + c)) * H_ + hh];
  concat_bf[(size_t)n * 2048 + H_ + hh] = f2bf(s);
}

// ---------------------------------------------------------------------------
// fc GEMM via MFMA bf16 (round-7 proven body, byte-identical) + fused softmax
// stats epilogue, transposed statsPart [n][bid*2].
// ---------------------------------------------------------------------------
__global__ __launch_bounds__(256) void k_fc_mfma(
    const float* __restrict__ W, const unsigned short* __restrict__ Zbf,
    const float* __restrict__ bias, float* __restrict__ outNV,
    float* __restrict__ statsPart) {
  const int t = threadIdx.x;
  const int v0 = blockIdx.x * 64;
  const int w = t >> 6, lane = t & 63;
  __shared__ __align__(16) unsigned char smem[16384];

  f32x4 acc[4] = {{0.f,0.f,0.f,0.f},{0.f,0.f,0.f,0.f},{0.f,0.f,0.f,0.f},{0.f,0.f,0.f,0.f}};

  // A staging: thread -> row ar (0..63), k-base (t&3)*16
  const int ar = t >> 2;
  const int ak = (t & 3) * 16;
  const float* aptr = W + (size_t)(v0 + ar) * 2048 + ak;
  const unsigned aslot0 = (unsigned)(ak >> 3);
  const unsigned awoff0 = ar * 128 + (((aslot0)     * 16) ^ ((ar & 7) << 4));
  const unsigned awoff1 = ar * 128 + (((aslot0 + 1) * 16) ^ ((ar & 7) << 4));
  // B staging: rows bn0, bn0+32; slot bs
  const int bn0 = t >> 3;
  const int bs = t & 7;
  const unsigned bwoff0 = 8192 + bn0 * 128        + ((bs * 16) ^ ((bn0 & 7) << 4));
  const unsigned bwoff1 = 8192 + (bn0 + 32) * 128 + ((bs * 16) ^ (((bn0 + 32) & 7) << 4));

  // fragment read offsets
  const int arow = (w << 4) + (lane & 15);
  const int ksub = lane >> 4;  // 0..3
  const unsigned aro[2] = {
    (unsigned)(arow * 128 + (((0 * 4 + ksub) * 16) ^ ((arow & 7) << 4))),
    (unsigned)(arow * 128 + (((1 * 4 + ksub) * 16) ^ ((arow & 7) << 4)))};
  unsigned bro[2][4];
#pragma unroll
  for (int kh = 0; kh < 2; kh++)
#pragma unroll
    for (int nf = 0; nf < 4; nf++) {
      int brow = nf * 16 + (lane & 15);
      bro[kh][nf] = 8192 + brow * 128 + (((kh * 4 + ksub) * 16) ^ ((brow & 7) << 4));
    }

  // prefetch k0 = 0
  float4 a0 = ((const float4*)aptr)[0];
  float4 a1 = ((const float4*)aptr)[1];
  float4 a2 = ((const float4*)aptr)[2];
  float4 a3 = ((const float4*)aptr)[3];
  uint4 bv0 = *(const uint4*)(Zbf + (size_t)bn0 * 2048 + bs * 8);
  uint4 bv1 = *(const uint4*)(Zbf + (size_t)(bn0 + 32) * 2048 + bs * 8);

  for (int k0 = 0; k0 < 2048; k0 += 64) {
    __syncthreads();
    uint4 pa0, pa1;
    pa0.x = pk2(a0.x, a0.y); pa0.y = pk2(a0.z, a0.w);
    pa0.z = pk2(a1.x, a1.y); pa0.w = pk2(a1.z, a1.w);
    pa1.x = pk2(a2.x, a2.y); pa1.y = pk2(a2.z, a2.w);
    pa1.z = pk2(a3.x, a3.y); pa1.w = pk2(a3.z, a3.w);
    *(uint4*)(smem + awoff0) = pa0;
    *(uint4*)(smem + awoff1) = pa1;
    *(uint4*)(smem + bwoff0) = bv0;
    *(uint4*)(smem + bwoff1) = bv1;
    if (k0 + 64 < 2048) {
      const float* ap = aptr + k0 + 64;
      a0 = ((const float4*)ap)[0];
      a1 = ((const float4*)ap)[1];
      a2 = ((const float4*)ap)[2];
      a3 = ((const float4*)ap)[3];
      bv0 = *(const uint4*)(Zbf + (size_t)bn0 * 2048 + (k0 + 64) + bs * 8);
      bv1 = *(const uint4*)(Zbf + (size_t)(bn0 + 32) * 2048 + (k0 + 64) + bs * 8);
    }
    __syncthreads();
#pragma unroll
    for (int kh = 0; kh < 2; kh++) {
      bf16x8 af = *(const bf16x8*)(smem + aro[kh]);
#pragma unroll
      for (int nf = 0; nf < 4; nf++) {
        bf16x8 bfr = *(const bf16x8*)(smem + bro[kh][nf]);
        acc[nf] = __builtin_amdgcn_mfma_f32_16x16x32_bf16(af, bfr, acc[nf], 0, 0, 0);
      }
    }
  }

  // epilogue: D col = lane&15 (n within frag), row = (lane>>4)*4 + reg (v)
  const int vrow = v0 + (w << 4) + ((lane >> 4) << 2);
  float4 b4 = *(const float4*)(bias + vrow);
  float vals[4][4];
#pragma unroll
  for (int nf = 0; nf < 4; nf++) {
    int n = nf * 16 + (lane & 15);
    vals[nf][0] = acc[nf][0] + b4.x; vals[nf][1] = acc[nf][1] + b4.y;
    vals[nf][2] = acc[nf][2] + b4.z; vals[nf][3] = acc[nf][3] + b4.w;
    *(float4*)(outNV + (size_t)n * V_ + vrow) =
        make_float4(vals[nf][0], vals[nf][1], vals[nf][2], vals[nf][3]);
  }

  // fused per-block softmax stats over this 64n x 64v tile
  __syncthreads();  // all frag reads done; reuse smem
  float* mx   = (float*)smem;            // [64][16]
  float* sm   = (float*)(smem + 4096);   // [64][16]
  float* bmax = (float*)(smem + 8192);   // [64]
  const int cidx = w * 4 + (lane >> 4);  // 16 contributors per n
#pragma unroll
  for (int nf = 0; nf < 4; nf++) {
    int n = nf * 16 + (lane & 15);
    float m = fmaxf(fmaxf(vals[nf][0], vals[nf][1]), fmaxf(vals[nf][2], vals[nf][3]));
    mx[n * 16 + cidx] = m;
  }
  __syncthreads();
  if (t < 64) {
    float m = mx[t * 16];
#pragma unroll
    for (int i = 1; i < 16; i++) m = fmaxf(m, mx[t * 16 + i]);
    bmax[t] = m;
  }
  __syncthreads();
#pragma unroll
  for (int nf = 0; nf < 4; nf++) {
    int n = nf * 16 + (lane & 15);
    float M = bmax[n];
    float s = expf(vals[nf][0] - M) + expf(vals[nf][1] - M) +
              expf(vals[nf][2] - M) + expf(vals[nf][3] - M);
    sm[n * 16 + cidx] = s;
  }
  __syncthreads();
  if (t < 64) {
    float s = 0.f;
#pragma unroll
    for (int i = 0; i < 16; i++) s += sm[t * 16 + i];
    statsPart[(size_t)t * 1024 + blockIdx.x * 2]     = bmax[t];
    statsPart[(size_t)t * 1024 + blockIdx.x * 2 + 1] = s;
  }
}

// ---------------------------------------------------------------------------
// Merged stats-combine + logp
// ---------------------------------------------------------------------------
__global__ __launch_bounds__(256) void k_logp_merged(
    float* __restrict__ logits, const float* __restrict__ statsPart) {
  const int n = blockIdx.y, t = threadIdx.x;
  const float2* sp = (const float2*)(statsPart + (size_t)n * 1024);

  float m = -INFINITY, s = 0.f;
#pragma unroll
  for (int rep = 0; rep < 2; rep++) {
    int p = rep * 256 + t;
    if (p < 500) {
      float2 e = sp[p];
      if (e.x > m) { s = s * expf(m - e.x) + e.y; m = e.x; }
      else         { s += e.y * expf(e.x - m); }
    }
  }
  __shared__ float ms[256], ss[256];
  ms[t] = m; ss[t] = s;
  __syncthreads();
  for (int off = 128; off; off >>= 1) {
    if (t < off) {
      float m2 = ms[t + off], s2 = ss[t + off];
      float M = fmaxf(ms[t], m2);
      ss[t] = ss[t] * expf(ms[t] - M) + s2 * expf(m2 - M);
      ms[t] = M;
    }
    __syncthreads();
  }
  const float sub = ms[0] + logf(ss[0]);

  const int v4 = blockIdx.x * 256 + t;  // float4 index, 8000 per row
  if (v4 < V_ / 4) {
    float4* p = (float4*)(logits + (size_t)n * V_) + v4;
    float4 x = *p;
    *p = make_float4(x.x - sub, x.y - sub, x.z - sub, x.w - sub);
  }
}

// ---------------------------------------------------------------------------
extern "C" void kernel_launch(void* const* d_in, const int* in_sizes, int n_in,
                              void* d_out, int out_size, void* d_ws, size_t ws_size,
                              hipStream_t stream) {
  const int*   prev_out = (const int*)d_in[0];
  const float* h0   = (const float*)d_in[1];
  const float* c0   = (const float*)d_in[2];
  const float* enc  = (const float*)d_in[3];
  const float* embW = (const float*)d_in[4];
  const float* w_ih = (const float*)d_in[5];
  const float* w_hh = (const float*)d_in[6];
  const float* b_ih = (const float*)d_in[7];
  const float* b_hh = (const float*)d_in[8];
  const float* fc_W = (const float*)d_in[9];
  const float* fc_b = (const float*)d_in[10];

  float* out = (float*)d_out;
  float* logp  = out;                       // N*V (logits -> logp in place)
  float* out_h = out + (size_t)N_ * V_;     // N*H
  float* out_c = out_h + (size_t)N_ * H_;   // N*H

  char* wsb = (char*)d_ws;
  float* gpart   = (float*)wsb; wsb += (size_t)8 * 4096 * 64 * 4;      // 8 MB
  float* ctxPart = (float*)wsb; wsb += (size_t)16 * 64 * H_ * 4;       // 4 MB
  unsigned short* concat_bf = (unsigned short*)wsb; wsb += (size_t)64 * 2048 * 2;
  float* statsPart = (float*)wsb; wsb += (size_t)64 * 1024 * 4;        // 256 KB

  // 1. gates (K-split x8 -> 512 blocks, in-kernel Z gather, transposed store)
  k_gemm64t<<<dim3(4096 / 64, 8), 256, 0, stream>>>(
      w_ih, w_hh, prev_out, embW, h0, gpart, 192);
  // 2. LSTM -> h,c (d_out), h -> concat_bf[.., 0:1024)
  k_lstm_fused<<<64 * H_ / 256, 256, 0, stream>>>(gpart, b_ih, b_hh, c0,
                                                  out_h, out_c, concat_bf);
  // 3. attention (single enc pass, r7 proven body)
  k_attn<<<dim3(16, 64), 256, 0, stream>>>(enc, out_h, ctxPart);
  // 4. ctx reduce -> concat_bf[.., 1024:2048)
  k_ctxreduce_bf<<<64 * H_ / 256, 256, 0, stream>>>(ctxPart, concat_bf);
  // 5. fc (round-7 body, fused softmax stats)
  k_fc_mfma<<<V_ / 64, 256, 0, stream>>>(fc_W, concat_bf, fc_b, logp, statsPart);
  // 6. merged stats-combine + in-place logp
  k_logp_merged<<<dim3((V_ / 4 + 255) / 256, N_), 256, 0, stream>>>(logp, statsPart);
}